// Round 3
// baseline (932.896 us; speedup 1.0000x reference)
//
#include <hip/hip_runtime.h>

#define HH   512
#define WW   512
#define CIN  16
#define COUT 16
#define KK   5

#define TLW  256          // output tile width
#define TLH  4            // output tile height
#define SR   8            // staged rows = TLH + 4 (halo 2 each side)
#define SC   264          // staged cols = TLW + 8 (c0-4 .. c0+259), 66 float4
#define SC4  (SC / 4)     // 66 float4 per row
#define NSLOT (SR * SC4)  // 528 float4 slots per ci

// out[n,o,h,w] = sum_i sum_{d=-2..2} fw[o,i,d+2] * x[n,i,h+d,w+d]  (zero pad)
//
// Block (64,4) = 256 threads -> 256x4 output tile, all 16 output channels.
// Single LDS buffer, register-staged double buffer over ci (T14 pattern):
//   issue global loads for ci+1  ->  compute ci from LDS  ->  barrier -> write.
__global__ __launch_bounds__(256) void diag_conv_kernel(
    const float* __restrict__ x, const float* __restrict__ fw,
    float* __restrict__ out)
{
    __shared__ float tile[SR][SC];
    float4* tile4 = reinterpret_cast<float4*>(&tile[0][0]);

    const int tx  = threadIdx.x;              // 0..63
    const int ty  = threadIdx.y;              // 0..3
    const int tid = ty * 64 + tx;             // 0..255

    // XCD-chunked swizzle: 4096 blocks, 8 XCDs, 512 blocks (=2 n-planes) each.
    // Vertically-overlapping tiles (bh, bh+1) land on the same XCD L2.
    const int id  = blockIdx.x;
    const int nid = (id & 7) * 512 + (id >> 3);   // bijective: 4096 % 8 == 0
    const int n   = nid >> 8;                     // 0..15
    const int rem = nid & 255;
    const int bh  = rem >> 1;                     // 0..127
    const int bx  = rem & 1;                      // 0..1

    const int h  = bh * TLH + ty;
    const int c0 = bx * TLW;

    // ---- staging geometry (ci-independent) ----
    // slot s: row = s / 66, c4 = s % 66; global row gr = bh*4 - 2 + row,
    // global col gc = c0 - 4 + 4*c4.  gc is always 4-aligned and HH/WW are
    // multiples of 4, so OOB is whole-float4: one bool per slot.
    int  off0, off1, off2;
    bool ok0, ok1, ok2;
    {
        int s   = tid;
        int row = s / SC4, c4 = s - row * SC4;
        int gr  = bh * TLH - 2 + row, gc = c0 - 4 + 4 * c4;
        ok0  = ((unsigned)gr < (unsigned)HH) & ((unsigned)gc < (unsigned)WW);
        off0 = (ok0 ? gr : 0) * WW + (ok0 ? gc : 0);
    }
    {
        int s   = tid + 256;
        int row = s / SC4, c4 = s - row * SC4;
        int gr  = bh * TLH - 2 + row, gc = c0 - 4 + 4 * c4;
        ok1  = ((unsigned)gr < (unsigned)HH) & ((unsigned)gc < (unsigned)WW);
        off1 = (ok1 ? gr : 0) * WW + (ok1 ? gc : 0);
    }
    {
        int s   = tid + 512;
        int row = s / SC4, c4 = s - row * SC4;
        int gr  = bh * TLH - 2 + row, gc = c0 - 4 + 4 * c4;
        ok2  = ((unsigned)gr < (unsigned)HH) & ((unsigned)gc < (unsigned)WW);
        off2 = (ok2 ? gr : 0) * WW + (ok2 ? gc : 0);
    }

    const float* xn = x + (size_t)n * (CIN * HH * WW);

    float acc[COUT][4];
#pragma unroll
    for (int o = 0; o < COUT; ++o)
#pragma unroll
        for (int p = 0; p < 4; ++p) acc[o][p] = 0.f;

    float4 stA[3], stB[3];

    auto loadci = [&](int i, float4* st) {
        const float* xi = xn + i * (HH * WW);
        st[0] = *reinterpret_cast<const float4*>(xi + off0);
        st[0].x = ok0 ? st[0].x : 0.f; st[0].y = ok0 ? st[0].y : 0.f;
        st[0].z = ok0 ? st[0].z : 0.f; st[0].w = ok0 ? st[0].w : 0.f;
        st[1] = *reinterpret_cast<const float4*>(xi + off1);
        st[1].x = ok1 ? st[1].x : 0.f; st[1].y = ok1 ? st[1].y : 0.f;
        st[1].z = ok1 ? st[1].z : 0.f; st[1].w = ok1 ? st[1].w : 0.f;
        if (tid < NSLOT - 512) {
            st[2] = *reinterpret_cast<const float4*>(xi + off2);
            st[2].x = ok2 ? st[2].x : 0.f; st[2].y = ok2 ? st[2].y : 0.f;
            st[2].z = ok2 ? st[2].z : 0.f; st[2].w = ok2 ? st[2].w : 0.f;
        }
    };

    auto storeci = [&](const float4* st) {
        tile4[tid]       = st[0];
        tile4[tid + 256] = st[1];
        if (tid < NSLOT - 512) tile4[tid + 512] = st[2];
    };

    auto compute = [&](int i) {
#pragma unroll
        for (int d = -2; d <= 2; ++d) {
            // local row = ty + d + 2 in [0,7]; local col = tx + p*64 + d + 4
            const float v0 = tile[ty + d + 2][tx       + d + 4];
            const float v1 = tile[ty + d + 2][tx +  64 + d + 4];
            const float v2 = tile[ty + d + 2][tx + 128 + d + 4];
            const float v3 = tile[ty + d + 2][tx + 192 + d + 4];
#pragma unroll
            for (int o = 0; o < COUT; ++o) {
                const float wt = fw[(o * CIN + i) * KK + (d + 2)]; // uniform -> s_load
                acc[o][0] = fmaf(wt, v0, acc[o][0]);
                acc[o][1] = fmaf(wt, v1, acc[o][1]);
                acc[o][2] = fmaf(wt, v2, acc[o][2]);
                acc[o][3] = fmaf(wt, v3, acc[o][3]);
            }
        }
    };

    loadci(0, stA);
#pragma unroll
    for (int i = 0; i < CIN; i += 2) {
        // write staged regs for ci=i, immediately issue loads for ci=i+1
        storeci(stA);
        loadci(i + 1, stB);          // in flight across compute(i)
        __syncthreads();             // LDS tile(i) visible
        compute(i);
        __syncthreads();             // everyone done reading tile(i)

        storeci(stB);
        if (i + 2 < CIN) loadci(i + 2, stA);
        __syncthreads();
        compute(i + 1);
        __syncthreads();
    }

    // Output is write-once streaming: nontemporal so 256 MiB of stores don't
    // evict the x-plane slices (halo reuse) from the XCD L2.
    float* on = out + (size_t)(n * COUT) * (HH * WW) + (size_t)h * WW + c0 + tx;
#pragma unroll
    for (int o = 0; o < COUT; ++o) {
#pragma unroll
        for (int p = 0; p < 4; ++p)
            __builtin_nontemporal_store(acc[o][p], &on[(size_t)o * (HH * WW) + p * 64]);
    }
}

extern "C" void kernel_launch(void* const* d_in, const int* in_sizes, int n_in,
                              void* d_out, int out_size, void* d_ws, size_t ws_size,
                              hipStream_t stream) {
    const float* x  = (const float*)d_in[0];   // [16,16,512,512] fp32
    const float* fw = (const float*)d_in[1];   // [16,16,5] fp32
    float* out = (float*)d_out;                // [16,16,512,512] fp32

    dim3 block(64, 4, 1);
    dim3 grid(4096, 1, 1);   // (2 w-tiles) x (128 h-tiles) x (16 n), swizzled in-kernel
    hipLaunchKernelGGL(diag_conv_kernel, grid, block, 0, stream, x, fw, out);
}

// Round 5
// 636.333 us; speedup vs baseline: 1.4660x; 1.4660x over previous
//
#include <hip/hip_runtime.h>

#define HH   512
#define WW   512
#define CIN  16
#define COUT 16
#define KK   5

#define TLW  256          // output tile width
#define TLH  4            // output tile height
#define SR   8            // staged rows = TLH + 4 halo
#define SC   264          // 4 pad | 256 body | 4 pad (body at col 4, 16B-aligned)

__device__ __forceinline__ void gll16(const float* g, float* l) {
    __builtin_amdgcn_global_load_lds(
        (const __attribute__((address_space(1))) unsigned int*)g,
        (__attribute__((address_space(3))) unsigned int*)l, 16, 0, 0);
}

// out[n,o,h,w] = sum_i sum_d fw[o,i,d+2] * x[n,i,h+d,w+d]   (zero pad)
// Block (64,4): 256x4 output tile, all 16 output channels.
// Double-buffered LDS, staged via global_load_lds (async DMA, no reg roundtrip):
//   stage(ci+1 -> other buf)  ||  compute(ci)  ->  one barrier per ci.
__global__ __launch_bounds__(256, 4) void diag_conv_kernel(
    const float* __restrict__ x, const float* __restrict__ fw,
    float* __restrict__ out)
{
    __shared__ float tile[2][SR][SC];

    const int tx  = threadIdx.x;              // 0..63 (= lane)
    const int ty  = threadIdx.y;              // 0..3  (= wave)
    const int tid = (ty << 6) | tx;

    // XCD-chunked bijective swizzle (4096 % 8 == 0): vertical neighbors share an XCD L2.
    const int id  = blockIdx.x;
    const int nid = (id & 7) * 512 + (id >> 3);
    const int n   = nid >> 8;
    const int rem = nid & 255;
    const int bh  = rem >> 1;                 // 0..127
    const int bx  = rem & 1;                  // 0..1

    const int h  = bh * TLH + ty;
    const int c0 = bx * TLW;

    const float* xn = x + (size_t)n * (CIN * HH * WW);

    // body staging: wave ty stages rows {ty, ty+4}; one gll16 each (64 lanes x 16B = 256 floats)
    const int  r0   = ty, r1 = ty + 4;
    const int  gr0  = bh * TLH - 2 + r0;
    const int  gr1  = bh * TLH - 2 + r1;
    const bool rok0 = (unsigned)gr0 < (unsigned)HH;   // wave-uniform
    const bool rok1 = (unsigned)gr1 < (unsigned)HH;
    const int  bo0  = gr0 * WW + c0 + tx * 4;         // per-lane float offset
    const int  bo1  = gr1 * WW + c0 + tx * 4;

    // halo cols (2 left + 2 right) x 8 rows = 32 values: first 32 lanes, register path
    int  hr = 0, hlc = 0, hoff = 0; bool hok = false;
    if (tid < 32) {
        hr = tid >> 2; const int k = tid & 3;
        hlc = (k < 2) ? (2 + k) : (258 + k);                  // LDS col 2,3,260,261
        const int gc = (k < 2) ? (c0 - 2 + k) : (c0 + 254 + k); // global col c0-2..-1, c0+256..257
        const int gr = bh * TLH - 2 + hr;
        hok  = ((unsigned)gr < (unsigned)HH) & ((unsigned)gc < (unsigned)WW);
        hoff = hok ? (gr * WW + gc) : 0;
    }

    float acc[COUT][4];
#pragma unroll
    for (int o = 0; o < COUT; ++o)
#pragma unroll
        for (int p = 0; p < 4; ++p) acc[o][p] = 0.f;

    auto stage = [&](int i, float (*T)[SC]) {
        const float* xi = xn + i * (HH * WW);
        if (rok0) gll16(xi + bo0, &T[r0][4]);     // uniform LDS base + lane*16
        else { float4 z{0.f, 0.f, 0.f, 0.f};
               *reinterpret_cast<float4*>(&T[r0][4 + tx * 4]) = z; }
        if (rok1) gll16(xi + bo1, &T[r1][4]);
        else { float4 z{0.f, 0.f, 0.f, 0.f};
               *reinterpret_cast<float4*>(&T[r1][4 + tx * 4]) = z; }
    };
    auto halo_load = [&](int i) -> float {        // issue early...
        float v = 0.f;
        if (tid < 32) { const float t = xn[i * (HH * WW) + hoff]; v = hok ? t : 0.f; }
        return v;
    };
    auto halo_write = [&](float (*T)[SC], float v) {  // ...write late (after compute)
        if (tid < 32) T[hr][hlc] = v;
    };

    auto compute = [&](int i, const float (*T)[SC]) {
#pragma unroll
        for (int d = -2; d <= 2; ++d) {
            // row ty+d+2 in [0,7]; cols tx+p*64+d+4 in [2,261]
            const float* Tr = &T[ty + d + 2][tx + d + 4];
            const float v0 = Tr[0], v1 = Tr[64], v2 = Tr[128], v3 = Tr[192];
            const float* fwd = fw + i * KK + (d + 2);
#pragma unroll
            for (int o = 0; o < COUT; ++o) {
                const float wt = fwd[o * (CIN * KK)];   // uniform -> s_load
                acc[o][0] = fmaf(wt, v0, acc[o][0]);
                acc[o][1] = fmaf(wt, v1, acc[o][1]);
                acc[o][2] = fmaf(wt, v2, acc[o][2]);
                acc[o][3] = fmaf(wt, v3, acc[o][3]);
            }
        }
    };

    {
        const float h0 = halo_load(0);
        stage(0, tile[0]);
        halo_write(tile[0], h0);
    }
    __syncthreads();

#pragma unroll 1
    for (int i = 0; i < CIN; i += 2) {
        const float hB = halo_load(i + 1);    // issue global loads for ci+1
        stage(i + 1, tile[1]);                //   (DMA in flight across compute)
        compute(i, tile[0]);
        halo_write(tile[1], hB);              // latency hidden under compute
        __syncthreads();                      // vmcnt(0)+lgkmcnt(0): tile[1] ready

        const bool more = (i + 2 < CIN);
        float hA = 0.f;
        if (more) { hA = halo_load(i + 2); stage(i + 2, tile[0]); }
        compute(i + 1, tile[1]);
        if (more) halo_write(tile[0], hA);
        __syncthreads();
    }

    // write-once streaming output: nontemporal keeps x resident in L2
    float* on = out + (size_t)(n * COUT) * (HH * WW) + (size_t)h * WW + c0 + tx;
#pragma unroll
    for (int o = 0; o < COUT; ++o)
#pragma unroll
        for (int p = 0; p < 4; ++p)
            __builtin_nontemporal_store(acc[o][p], &on[(size_t)o * (HH * WW) + p * 64]);
}

extern "C" void kernel_launch(void* const* d_in, const int* in_sizes, int n_in,
                              void* d_out, int out_size, void* d_ws, size_t ws_size,
                              hipStream_t stream) {
    const float* x  = (const float*)d_in[0];   // [16,16,512,512] fp32
    const float* fw = (const float*)d_in[1];   // [16,16,5] fp32
    float* out = (float*)d_out;                // [16,16,512,512] fp32

    dim3 block(64, 4, 1);
    dim3 grid(4096, 1, 1);   // (2 w-tiles) x (128 h-tiles) x (16 n), swizzled in-kernel
    hipLaunchKernelGGL(diag_conv_kernel, grid, block, 0, stream, x, fw, out);
}